// Round 6
// baseline (285.169 us; speedup 1.0000x reference)
//
#include <hip/hip_runtime.h>
#include <hip/hip_bf16.h>

#define T_SEQ 4096
#define EMB 1024
#define NH 16
#define HD 64
#define DEFER_THR 10.0f

typedef float f32x4 __attribute__((ext_vector_type(4)));
typedef float f32x16 __attribute__((ext_vector_type(16)));
typedef short short8 __attribute__((ext_vector_type(8)));
typedef short short4v __attribute__((ext_vector_type(4)));

__device__ inline unsigned short f2bf(float f) {
  union { float f; unsigned u; } a; a.f = f;
  unsigned r = a.u + 0x7fffu + ((a.u >> 16) & 1u);
  return (unsigned short)(r >> 16);
}
#if __has_builtin(__builtin_amdgcn_exp2f)
#define EXP2F(x) __builtin_amdgcn_exp2f(x)
#else
#define EXP2F(x) exp2f(x)
#endif
#define GLL16(g, l) __builtin_amdgcn_global_load_lds( \
    (const __attribute__((address_space(1))) void*)(g), \
    (__attribute__((address_space(3))) void*)(l), 16, 0, 0)

// ---------------- cast x (f32 -> bf16) ----------------
__global__ __launch_bounds__(256) void cast_x_kernel(const float* __restrict__ in,
                                                     unsigned short* __restrict__ out) {
  int i = (blockIdx.x * 256 + threadIdx.x) * 8;
  float4 a = *(const float4*)(in + i);
  float4 b = *(const float4*)(in + i + 4);
  uint4 o;
  o.x = f2bf(a.x) | ((unsigned)f2bf(a.y) << 16);
  o.y = f2bf(a.z) | ((unsigned)f2bf(a.w) << 16);
  o.z = f2bf(b.x) | ((unsigned)f2bf(b.y) << 16);
  o.w = f2bf(b.z) | ((unsigned)f2bf(b.w) << 16);
  *(uint4*)(out + i) = o;
}

// ---------------- transpose + cast W (f32 [K][N] -> bf16 [N][K]) ----------------
__global__ __launch_bounds__(256) void transpose_cast_kernel(const float* __restrict__ Wq,
                                                             const float* __restrict__ Wk,
                                                             const float* __restrict__ Wv,
                                                             unsigned short* __restrict__ WTall) {
  int z = blockIdx.z;
  const float* W = (z == 0) ? Wq : ((z == 1) ? Wk : Wv);
  unsigned short* WT = WTall + (size_t)z * EMB * EMB;
  __shared__ unsigned short tile[32][33];
  int tx = threadIdx.x & 31, ty = threadIdx.x >> 5;
  int bn = blockIdx.x * 32, bk = blockIdx.y * 32;
#pragma unroll
  for (int p = 0; p < 4; p++)
    tile[ty + p * 8][tx] = f2bf(W[(size_t)(bk + ty + p * 8) * EMB + bn + tx]);
  __syncthreads();
#pragma unroll
  for (int p = 0; p < 4; p++)
    WT[(size_t)(bn + ty + p * 8) * EMB + bk + tx] = tile[tx][ty + p * 8];
}

// ---------------- bf16 V [t][e] -> VT [e][t] ----------------
__global__ __launch_bounds__(256) void transpose_v_kernel(const unsigned short* __restrict__ V,
                                                          unsigned short* __restrict__ VT) {
  int h = blockIdx.z;
  int t0 = blockIdx.x * 32, d0 = blockIdx.y * 32;
  __shared__ unsigned short tl[32][33];
  int tx = threadIdx.x & 31, ty = threadIdx.x >> 5;
#pragma unroll
  for (int p = 0; p < 4; p++)
    tl[ty + p * 8][tx] = V[(size_t)(t0 + ty + p * 8) * EMB + h * HD + d0 + tx];
  __syncthreads();
#pragma unroll
  for (int p = 0; p < 4; p++)
    VT[(size_t)(h * HD + d0 + ty + p * 8) * T_SEQ + t0 + tx] = tl[tx][ty + p * 8];
}

// ---------------- QKV GEMM (m97-style global_load_lds staging) ----------------
// z=0 -> Q (scaled by 0.125*log2e), z=1 -> K, z=2 -> V (all row-major coalesced)
__global__ __launch_bounds__(256) void gemm_qkv(const unsigned short* __restrict__ Xb,
                                                const unsigned short* __restrict__ WTall,
                                                unsigned short* __restrict__ QKV) {
  int z = blockIdx.z;
  const unsigned short* Bt = WTall + (size_t)z * EMB * EMB;
  unsigned short* Out = QKV + (size_t)z * T_SEQ * EMB;

  __shared__ __align__(16) unsigned short sA[128 * 32];
  __shared__ __align__(16) unsigned short sB[128 * 32];

  int m0 = blockIdx.x * 128, n0 = blockIdx.y * 128;
  int tid = threadIdx.x;
  int lane = tid & 63, wid = tid >> 6;
  int wr = wid >> 1, wc = wid & 1;
  int fr = lane & 15, fq = lane >> 4;

  int r0 = tid >> 2, o0 = (tid & 3) * 8;
  int r1 = (tid + 256) >> 2;

  f32x4 acc[4][4] = {};

  for (int k0 = 0; k0 < EMB; k0 += 32) {
    __syncthreads();
    GLL16(Xb + (size_t)(m0 + r0) * EMB + k0 + o0, sA + (size_t)tid * 8);
    GLL16(Xb + (size_t)(m0 + r1) * EMB + k0 + o0, sA + (size_t)(tid + 256) * 8);
    GLL16(Bt + (size_t)(n0 + r0) * EMB + k0 + o0, sB + (size_t)tid * 8);
    GLL16(Bt + (size_t)(n0 + r1) * EMB + k0 + o0, sB + (size_t)(tid + 256) * 8);
    asm volatile("s_waitcnt vmcnt(0)" ::: "memory");
    __syncthreads();

    short8 aF[4], bF[4];
#pragma unroll
    for (int i = 0; i < 4; i++) {
      aF[i] = *(const short8*)(sA + (wr * 64 + i * 16 + fr) * 32 + fq * 8);
      bF[i] = *(const short8*)(sB + (wc * 64 + i * 16 + fr) * 32 + fq * 8);
    }
#pragma unroll
    for (int i = 0; i < 4; i++)
#pragma unroll
      for (int j = 0; j < 4; j++)
        acc[i][j] = __builtin_amdgcn_mfma_f32_16x16x32_bf16(aF[i], bF[j], acc[i][j], 0, 0, 0);
  }

  float scale = (z == 0) ? 0.1803368801111204f : 1.0f;  // 0.125 * log2(e) for Q
#pragma unroll
  for (int i = 0; i < 4; i++)
#pragma unroll
    for (int j = 0; j < 4; j++)
#pragma unroll
      for (int r = 0; r < 4; r++) {
        int row = m0 + wr * 64 + i * 16 + fq * 4 + r;
        int col = n0 + wc * 64 + j * 16 + fr;
        Out[(size_t)row * EMB + col] = f2bf(acc[i][j][r] * scale);
      }
}

// ---------------- causal flash attention, swapped-QK 32x32x16 ----------------
// grid (128, 16): one 32-q column per block, 4 waves = 4-way kv split (ss = w mod 4).
// No barriers in the main loop; partials merged in LDS at the end.
__global__ __launch_bounds__(256, 4) void attn_kernel(const unsigned short* __restrict__ Qb,
                                                      const unsigned short* __restrict__ Kb,
                                                      const unsigned short* __restrict__ VTg,
                                                      float* __restrict__ out) {
  int c = (gridDim.x - 1) - blockIdx.x;  // long columns dispatch first
  int h = blockIdx.y;
  int tid = threadIdx.x;
  int lane = tid & 63, w = tid >> 6;
  int ql = lane & 31, hi = lane >> 5;
  int wq0 = c * 32, qg = wq0 + ql;

  __shared__ __align__(16) float smemf[4608];  // 18432 B
  unsigned short* sP = (unsigned short*)smemf + w * 1280;  // per-wave [32 q][32 kv] pad 40
  float* bufA = smemf;          // 32 x 68 f32 (combine, after loop)
  float* bufB = smemf + 2176;
  float* sM = smemf + 4352;     // 4 x 32
  float* sL = smemf + 4480;     // 4 x 32

  short8 qf[4];  // B-frags of Q: Q[q=ql][d = ks*16 + hi*8 + j]
#pragma unroll
  for (int ks = 0; ks < 4; ks++)
    qf[ks] = *(const short8*)(Qb + (size_t)qg * EMB + h * HD + ks * 16 + hi * 8);

  f32x16 oT0 = {}, oT1 = {};  // O^T accumulators, d-tiles 0/1, col = q = ql
  float m = -1e30f, lsum = 0.f;

  for (int ss = w; ss <= c; ss += 4) {
    int kvs = ss * 32;
    // K fragments direct from global (A-operand: K[kv = kvs+ql][d])
    const unsigned short* kbase = Kb + (size_t)(kvs + ql) * EMB + h * HD + hi * 8;
    short8 kf0 = *(const short8*)(kbase);
    short8 kf1 = *(const short8*)(kbase + 16);
    short8 kf2 = *(const short8*)(kbase + 32);
    short8 kf3 = *(const short8*)(kbase + 48);
    // V^T fragments direct from global (A-operand of PV)
    const unsigned short* vbase = VTg + (size_t)(h * HD + ql) * T_SEQ + kvs + hi * 8;
    short8 v00 = *(const short8*)(vbase);
    short8 v01 = *(const short8*)(vbase + 16);
    short8 v10 = *(const short8*)(vbase + 32 * T_SEQ);
    short8 v11 = *(const short8*)(vbase + 32 * T_SEQ + 16);

    f32x16 st = {};
    __builtin_amdgcn_s_setprio(1);
    st = __builtin_amdgcn_mfma_f32_32x32x16_bf16(kf0, qf[0], st, 0, 0, 0);
    st = __builtin_amdgcn_mfma_f32_32x32x16_bf16(kf1, qf[1], st, 0, 0, 0);
    st = __builtin_amdgcn_mfma_f32_32x32x16_bf16(kf2, qf[2], st, 0, 0, 0);
    st = __builtin_amdgcn_mfma_f32_32x32x16_bf16(kf3, qf[3], st, 0, 0, 0);
    __builtin_amdgcn_s_setprio(0);

    if (ss == c) {  // diagonal slice: mask kv > q
#pragma unroll
      for (int r = 0; r < 16; r++) {
        int kvg = kvs + (r & 3) + 8 * (r >> 2) + 4 * hi;
        if (kvg > qg) st[r] = -1e30f;
      }
    }
    // max-reduce tree
    float a0 = fmaxf(fmaxf(st[0], st[1]), st[2]);
    float a1 = fmaxf(fmaxf(st[3], st[4]), st[5]);
    float a2 = fmaxf(fmaxf(st[6], st[7]), st[8]);
    float a3 = fmaxf(fmaxf(st[9], st[10]), st[11]);
    float a4 = fmaxf(fmaxf(st[12], st[13]), st[14]);
    float mt = fmaxf(fmaxf(fmaxf(a0, a1), a2), fmaxf(fmaxf(a3, a4), st[15]));
    mt = fmaxf(mt, __shfl_xor(mt, 32));
    if (!__all(mt - m <= DEFER_THR)) {  // defer-max (T13)
      float mnew = fmaxf(m, mt);
      float al = EXP2F(m - mnew);
      lsum *= al;
#pragma unroll
      for (int r = 0; r < 16; r++) { oT0[r] *= al; oT1[r] *= al; }
      m = mnew;
    }
#pragma unroll
    for (int r = 0; r < 16; r++) st[r] = EXP2F(st[r] - m);
    float s0 = (st[0] + st[1]) + (st[2] + st[3]);
    float s1 = (st[4] + st[5]) + (st[6] + st[7]);
    float s2 = (st[8] + st[9]) + (st[10] + st[11]);
    float s3 = (st[12] + st[13]) + (st[14] + st[15]);
    float ls = (s0 + s1) + (s2 + s3);
    ls += __shfl_xor(ls, 32);
    lsum += ls;

    // P^T -> bf16 via per-wave LDS round-trip: sP[q=ql][kv_local]
#pragma unroll
    for (int g = 0; g < 4; g++) {
      __hip_bfloat162 plo = __float22bfloat162_rn(float2{st[g * 4 + 0], st[g * 4 + 1]});
      __hip_bfloat162 phi = __float22bfloat162_rn(float2{st[g * 4 + 2], st[g * 4 + 3]});
      union { __hip_bfloat162 hh[2]; short4v s4; } u4;
      u4.hh[0] = plo; u4.hh[1] = phi;
      *(short4v*)(sP + ql * 40 + g * 8 + hi * 4) = u4.s4;
    }
    asm volatile("s_waitcnt lgkmcnt(0)" ::: "memory");  // wave-local round-trip
    __builtin_amdgcn_sched_barrier(0);

    short8 pa0 = *(const short8*)(sP + ql * 40 + hi * 8);
    short8 pa1 = *(const short8*)(sP + ql * 40 + 16 + hi * 8);
    __builtin_amdgcn_s_setprio(1);
    oT0 = __builtin_amdgcn_mfma_f32_32x32x16_bf16(v00, pa0, oT0, 0, 0, 0);
    oT1 = __builtin_amdgcn_mfma_f32_32x32x16_bf16(v10, pa0, oT1, 0, 0, 0);
    oT0 = __builtin_amdgcn_mfma_f32_32x32x16_bf16(v01, pa1, oT0, 0, 0, 0);
    oT1 = __builtin_amdgcn_mfma_f32_32x32x16_bf16(v11, pa1, oT1, 0, 0, 0);
    __builtin_amdgcn_s_setprio(0);
  }

  // ---- combine 4 kv-split partials ----
  if (hi == 0) { sM[w * 32 + ql] = m; sL[w * 32 + ql] = lsum; }
  __syncthreads();  // bar1: stats visible; loop done for all waves (sP dead)
  float m0 = sM[ql], m1 = sM[32 + ql], m2 = sM[64 + ql], m3 = sM[96 + ql];
  float mF = fmaxf(fmaxf(m0, m1), fmaxf(m2, m3));
  float lF = sL[ql] * EXP2F(m0 - mF) + sL[32 + ql] * EXP2F(m1 - mF) +
             sL[64 + ql] * EXP2F(m2 - mF) + sL[96 + ql] * EXP2F(m3 - mF);
  float fac = EXP2F(m - mF) / lF;

  float* buf = (w < 2) ? bufA : bufB;
  if ((w & 1) == 0) {
#pragma unroll
    for (int r = 0; r < 16; r++) {
      int dl = (r & 3) + 8 * (r >> 2) + 4 * hi;
      buf[ql * 68 + dl] = oT0[r] * fac;
      buf[ql * 68 + 32 + dl] = oT1[r] * fac;
    }
  }
  __syncthreads();  // bar2
  if (w & 1) {
#pragma unroll
    for (int r = 0; r < 16; r++) {
      int dl = (r & 3) + 8 * (r >> 2) + 4 * hi;
      buf[ql * 68 + dl] += oT0[r] * fac;
      buf[ql * 68 + 32 + dl] += oT1[r] * fac;
    }
  }
  __syncthreads();  // bar3
  for (int i = tid; i < 2048; i += 256) {
    int q = i >> 6, d = i & 63;
    bufA[q * 68 + d] += bufB[q * 68 + d];
  }
  __syncthreads();  // bar4
  int q = tid >> 3, c8 = (tid & 7) * 8;
  f32x4 va = *(const f32x4*)(bufA + q * 68 + c8);
  f32x4 vb = *(const f32x4*)(bufA + q * 68 + c8 + 4);
  *(f32x4*)(out + (size_t)(wq0 + q) * EMB + h * HD + c8) = va;
  *(f32x4*)(out + (size_t)(wq0 + q) * EMB + h * HD + c8 + 4) = vb;
}

extern "C" void kernel_launch(void* const* d_in, const int* in_sizes, int n_in,
                              void* d_out, int out_size, void* d_ws, size_t ws_size,
                              hipStream_t stream) {
  const float* x  = (const float*)d_in[0];
  const float* Wq = (const float*)d_in[1];
  const float* Wk = (const float*)d_in[2];
  const float* Wv = (const float*)d_in[3];
  float* out = (float*)d_out;

  unsigned short* Qb = (unsigned short*)d_ws;
  unsigned short* Kb = Qb + (size_t)T_SEQ * EMB;
  unsigned short* Vb = Kb + (size_t)T_SEQ * EMB;   // plain V from gemm (z=2)
  unsigned short* VT = Vb + (size_t)T_SEQ * EMB;   // VT[1024][4096]
  unsigned short* Xb = VT + (size_t)T_SEQ * EMB;
  unsigned short* WT = Xb + (size_t)T_SEQ * EMB;   // 3 x EMB*EMB bf16

  cast_x_kernel<<<(T_SEQ * EMB) / (256 * 8), 256, 0, stream>>>(x, Xb);
  dim3 tg(EMB / 32, EMB / 32, 3);
  transpose_cast_kernel<<<tg, 256, 0, stream>>>(Wq, Wk, Wv, WT);
  dim3 gg(T_SEQ / 128, EMB / 128, 3);
  gemm_qkv<<<gg, 256, 0, stream>>>(Xb, WT, Qb);
  dim3 tv(T_SEQ / 32, HD / 32, NH);
  transpose_v_kernel<<<tv, 256, 0, stream>>>(Vb, VT);
  dim3 ag(T_SEQ / 32, NH);
  attn_kernel<<<ag, 256, 0, stream>>>(Qb, Kb, VT, out);
}

// Round 7
// 245.435 us; speedup vs baseline: 1.1619x; 1.1619x over previous
//
#include <hip/hip_runtime.h>
#include <hip/hip_bf16.h>

#define T_SEQ 4096
#define EMB 1024
#define NH 16
#define HD 64
#define QBLK 128
#define KVB 64
#define DEFER_THR 10.0f

typedef float f32x4 __attribute__((ext_vector_type(4)));
typedef float f32x16 __attribute__((ext_vector_type(16)));
typedef short short8 __attribute__((ext_vector_type(8)));
typedef short short4v __attribute__((ext_vector_type(4)));

__device__ inline unsigned short f2bf(float f) {
  union { float f; unsigned u; } a; a.f = f;
  unsigned r = a.u + 0x7fffu + ((a.u >> 16) & 1u);
  return (unsigned short)(r >> 16);
}
#if __has_builtin(__builtin_amdgcn_exp2f)
#define EXP2F(x) __builtin_amdgcn_exp2f(x)
#else
#define EXP2F(x) exp2f(x)
#endif
#define GLL16(g, l) __builtin_amdgcn_global_load_lds( \
    (const __attribute__((address_space(1))) void*)(g), \
    (__attribute__((address_space(3))) void*)(l), 16, 0, 0)

// ---------------- cast x (f32 -> bf16) ----------------
__global__ __launch_bounds__(256) void cast_x_kernel(const float* __restrict__ in,
                                                     unsigned short* __restrict__ out) {
  int i = (blockIdx.x * 256 + threadIdx.x) * 8;
  float4 a = *(const float4*)(in + i);
  float4 b = *(const float4*)(in + i + 4);
  uint4 o;
  o.x = f2bf(a.x) | ((unsigned)f2bf(a.y) << 16);
  o.y = f2bf(a.z) | ((unsigned)f2bf(a.w) << 16);
  o.z = f2bf(b.x) | ((unsigned)f2bf(b.y) << 16);
  o.w = f2bf(b.z) | ((unsigned)f2bf(b.w) << 16);
  *(uint4*)(out + i) = o;
}

// ---------------- transpose + cast W (f32 [K][N] -> bf16 [N][K]) ----------------
__global__ __launch_bounds__(256) void transpose_cast_kernel(const float* __restrict__ Wq,
                                                             const float* __restrict__ Wk,
                                                             const float* __restrict__ Wv,
                                                             unsigned short* __restrict__ WTall) {
  int z = blockIdx.z;
  const float* W = (z == 0) ? Wq : ((z == 1) ? Wk : Wv);
  unsigned short* WT = WTall + (size_t)z * EMB * EMB;
  __shared__ unsigned short tile[32][33];
  int tx = threadIdx.x & 31, ty = threadIdx.x >> 5;
  int bn = blockIdx.x * 32, bk = blockIdx.y * 32;
#pragma unroll
  for (int p = 0; p < 4; p++)
    tile[ty + p * 8][tx] = f2bf(W[(size_t)(bk + ty + p * 8) * EMB + bn + tx]);
  __syncthreads();
#pragma unroll
  for (int p = 0; p < 4; p++)
    WT[(size_t)(bn + ty + p * 8) * EMB + bk + tx] = tile[tx][ty + p * 8];
}

// ---------------- bf16 V [t][e] -> VT [e][t] ----------------
__global__ __launch_bounds__(256) void transpose_v_kernel(const unsigned short* __restrict__ V,
                                                          unsigned short* __restrict__ VT) {
  int h = blockIdx.z;
  int t0 = blockIdx.x * 32, d0 = blockIdx.y * 32;
  __shared__ unsigned short tl[32][33];
  int tx = threadIdx.x & 31, ty = threadIdx.x >> 5;
#pragma unroll
  for (int p = 0; p < 4; p++)
    tl[ty + p * 8][tx] = V[(size_t)(t0 + ty + p * 8) * EMB + h * HD + d0 + tx];
  __syncthreads();
#pragma unroll
  for (int p = 0; p < 4; p++)
    VT[(size_t)(h * HD + d0 + ty + p * 8) * T_SEQ + t0 + tx] = tl[tx][ty + p * 8];
}

// ---------------- QKV GEMM (m97-style global_load_lds staging) ----------------
__global__ __launch_bounds__(256) void gemm_qkv(const unsigned short* __restrict__ Xb,
                                                const unsigned short* __restrict__ WTall,
                                                unsigned short* __restrict__ QKV) {
  int z = blockIdx.z;
  const unsigned short* Bt = WTall + (size_t)z * EMB * EMB;
  unsigned short* Out = QKV + (size_t)z * T_SEQ * EMB;

  __shared__ __align__(16) unsigned short sA[128 * 32];
  __shared__ __align__(16) unsigned short sB[128 * 32];

  int m0 = blockIdx.x * 128, n0 = blockIdx.y * 128;
  int tid = threadIdx.x;
  int lane = tid & 63, wid = tid >> 6;
  int wr = wid >> 1, wc = wid & 1;
  int fr = lane & 15, fq = lane >> 4;

  int r0 = tid >> 2, o0 = (tid & 3) * 8;
  int r1 = (tid + 256) >> 2;

  f32x4 acc[4][4] = {};

  for (int k0 = 0; k0 < EMB; k0 += 32) {
    __syncthreads();
    GLL16(Xb + (size_t)(m0 + r0) * EMB + k0 + o0, sA + (size_t)tid * 8);
    GLL16(Xb + (size_t)(m0 + r1) * EMB + k0 + o0, sA + (size_t)(tid + 256) * 8);
    GLL16(Bt + (size_t)(n0 + r0) * EMB + k0 + o0, sB + (size_t)tid * 8);
    GLL16(Bt + (size_t)(n0 + r1) * EMB + k0 + o0, sB + (size_t)(tid + 256) * 8);
    asm volatile("s_waitcnt vmcnt(0)" ::: "memory");
    __syncthreads();

    short8 aF[4], bF[4];
#pragma unroll
    for (int i = 0; i < 4; i++) {
      aF[i] = *(const short8*)(sA + (wr * 64 + i * 16 + fr) * 32 + fq * 8);
      bF[i] = *(const short8*)(sB + (wc * 64 + i * 16 + fr) * 32 + fq * 8);
    }
#pragma unroll
    for (int i = 0; i < 4; i++)
#pragma unroll
      for (int j = 0; j < 4; j++)
        acc[i][j] = __builtin_amdgcn_mfma_f32_16x16x32_bf16(aF[i], bF[j], acc[i][j], 0, 0, 0);
  }

  float scale = (z == 0) ? 0.1803368801111204f : 1.0f;  // 0.125 * log2(e) for Q
#pragma unroll
  for (int i = 0; i < 4; i++)
#pragma unroll
    for (int j = 0; j < 4; j++)
#pragma unroll
      for (int r = 0; r < 4; r++) {
        int row = m0 + wr * 64 + i * 16 + fq * 4 + r;
        int col = n0 + wc * 64 + j * 16 + fr;
        Out[(size_t)row * EMB + col] = f2bf(acc[i][j][r] * scale);
      }
}

// ---------------- causal flash attention, swapped-QK 32x32x16, kv-split ----------------
// grid (32, 16, 2): block (c,z) = q rows [c*128, c*128+128), kv tiles t = z, z+2, ... < 2c+2.
// 4 waves x 32 q; LDS-staged K/V^T; T14 prefetch; raw partials to workspace.
__global__ __launch_bounds__(256) void attn_kernel(const unsigned short* __restrict__ Qb,
                                                   const unsigned short* __restrict__ Kb,
                                                   const unsigned short* __restrict__ VTg,
                                                   float* __restrict__ Opart,
                                                   float* __restrict__ Mst,
                                                   float* __restrict__ Lst) {
  int c = (gridDim.x - 1) - blockIdx.x;  // long columns dispatch first
  int h = blockIdx.y;
  int z = blockIdx.z;
  int q0 = c * QBLK;
  int tid = threadIdx.x;
  int lane = tid & 63, w = tid >> 6;
  int ql = lane & 31, hi = lane >> 5;

  __shared__ __align__(16) unsigned short smem[14336];  // 28672 B
  unsigned short* sK = smem;                      // [64][72]
  unsigned short* sVT = smem + 64 * 72;           // [64][72] (V^T: [d][kv])
  unsigned short* sP = smem + 2 * 64 * 72 + w * (32 * 40);  // per-wave [32 q][32 kv] pad 40

  int wq0 = q0 + w * 32;
  int qg = wq0 + ql;

  short8 qf[4];  // B-frags of Q: Q[q=ql][d = ks*16 + hi*8 + j]
#pragma unroll
  for (int ks = 0; ks < 4; ks++)
    qf[ks] = *(const short8*)(Qb + (size_t)qg * EMB + h * HD + ks * 16 + hi * 8);

  f32x16 oT0 = {}, oT1 = {};  // O^T accumulators, d-tiles 0/1, col = q = ql
  float m = -1e30f, lsum = 0.f;

  int sr = tid >> 3;            // staging: 8 lanes x 16B = one 128B row
  int scs = (tid & 7) * 8;

  int wqmax = wq0 + 31;
  int ntot = 2 * c + 2;

  // prologue: issue loads for first owned tile (t = z)
  {
    int kv0 = z * KVB;
    short8 ka = *(const short8*)(Kb + (size_t)(kv0 + sr) * EMB + h * HD + scs);
    short8 kb = *(const short8*)(Kb + (size_t)(kv0 + sr + 32) * EMB + h * HD + scs);
    short8 va = *(const short8*)(VTg + (size_t)(h * HD + sr) * T_SEQ + kv0 + scs);
    short8 vb = *(const short8*)(VTg + (size_t)(h * HD + sr + 32) * T_SEQ + kv0 + scs);

    for (int t = z; t < ntot; t += 2) {
      int kv0c = t * KVB;
      __syncthreads();  // all waves done reading previous tile
      *(short8*)(sK + sr * 72 + scs) = ka;
      *(short8*)(sK + (sr + 32) * 72 + scs) = kb;
      *(short8*)(sVT + sr * 72 + scs) = va;
      *(short8*)(sVT + (sr + 32) * 72 + scs) = vb;
      __syncthreads();  // publish

      if (t + 2 < ntot) {  // prefetch next owned tile
        int kv1 = kv0c + 2 * KVB;
        ka = *(const short8*)(Kb + (size_t)(kv1 + sr) * EMB + h * HD + scs);
        kb = *(const short8*)(Kb + (size_t)(kv1 + sr + 32) * EMB + h * HD + scs);
        va = *(const short8*)(VTg + (size_t)(h * HD + sr) * T_SEQ + kv1 + scs);
        vb = *(const short8*)(VTg + (size_t)(h * HD + sr + 32) * T_SEQ + kv1 + scs);
      }

#pragma unroll
      for (int s = 0; s < 2; s++) {
        int kvs = kv0c + s * 32;
        if (kvs <= wqmax) {  // wave-uniform causal skip
          f32x16 st = {};
          __builtin_amdgcn_s_setprio(1);
#pragma unroll
          for (int ks = 0; ks < 4; ks++) {
            short8 kf = *(const short8*)(sK + (s * 32 + ql) * 72 + ks * 16 + hi * 8);
            st = __builtin_amdgcn_mfma_f32_32x32x16_bf16(kf, qf[ks], st, 0, 0, 0);
          }
          __builtin_amdgcn_s_setprio(0);
          if (kvs + 31 > wq0) {  // diagonal tile: mask kv > q
#pragma unroll
            for (int r = 0; r < 16; r++) {
              int kvg = kvs + (r & 3) + 8 * (r >> 2) + 4 * hi;
              if (kvg > qg) st[r] = -1e30f;
            }
          }
          float a0 = fmaxf(fmaxf(st[0], st[1]), st[2]);
          float a1 = fmaxf(fmaxf(st[3], st[4]), st[5]);
          float a2 = fmaxf(fmaxf(st[6], st[7]), st[8]);
          float a3 = fmaxf(fmaxf(st[9], st[10]), st[11]);
          float a4 = fmaxf(fmaxf(st[12], st[13]), st[14]);
          float mt = fmaxf(fmaxf(fmaxf(a0, a1), a2), fmaxf(fmaxf(a3, a4), st[15]));
          mt = fmaxf(mt, __shfl_xor(mt, 32));
          if (!__all(mt - m <= DEFER_THR)) {  // defer-max (T13)
            float mnew = fmaxf(m, mt);
            float al = EXP2F(m - mnew);
            lsum *= al;
#pragma unroll
            for (int r = 0; r < 16; r++) { oT0[r] *= al; oT1[r] *= al; }
            m = mnew;
          }
#pragma unroll
          for (int r = 0; r < 16; r++) st[r] = EXP2F(st[r] - m);
          float s0 = (st[0] + st[1]) + (st[2] + st[3]);
          float s1 = (st[4] + st[5]) + (st[6] + st[7]);
          float s2 = (st[8] + st[9]) + (st[10] + st[11]);
          float s3 = (st[12] + st[13]) + (st[14] + st[15]);
          float ls = (s0 + s1) + (s2 + s3);
          ls += __shfl_xor(ls, 32);
          lsum += ls;

          // P^T -> bf16 via per-wave LDS round-trip: sP[q=ql][kv_local]
#pragma unroll
          for (int g = 0; g < 4; g++) {
            __hip_bfloat162 plo = __float22bfloat162_rn(float2{st[g * 4 + 0], st[g * 4 + 1]});
            __hip_bfloat162 phi = __float22bfloat162_rn(float2{st[g * 4 + 2], st[g * 4 + 3]});
            union { __hip_bfloat162 hh[2]; short4v s4; } u4;
            u4.hh[0] = plo; u4.hh[1] = phi;
            *(short4v*)(sP + ql * 40 + g * 8 + hi * 4) = u4.s4;
          }
          asm volatile("s_waitcnt lgkmcnt(0)" ::: "memory");  // wave-local round-trip
          __builtin_amdgcn_sched_barrier(0);

          __builtin_amdgcn_s_setprio(1);
#pragma unroll
          for (int ksp = 0; ksp < 2; ksp++) {
            short8 pa = *(const short8*)(sP + ql * 40 + ksp * 16 + hi * 8);
            int cb = s * 32 + ksp * 16 + hi * 8;
            short8 v0 = *(const short8*)(sVT + (0 * 32 + ql) * 72 + cb);
            short8 v1 = *(const short8*)(sVT + (1 * 32 + ql) * 72 + cb);
            oT0 = __builtin_amdgcn_mfma_f32_32x32x16_bf16(v0, pa, oT0, 0, 0, 0);
            oT1 = __builtin_amdgcn_mfma_f32_32x32x16_bf16(v1, pa, oT1, 0, 0, 0);
          }
          __builtin_amdgcn_s_setprio(0);
        }
      }
    }
  }

  // stats
  if (hi == 0) {
    Mst[((size_t)z * NH + h) * T_SEQ + qg] = m;
    Lst[((size_t)z * NH + h) * T_SEQ + qg] = lsum;
  }

  // epilogue: transpose raw O^T -> O through LDS, coalesced f32x4 stores to Opart
  float* Od = Opart + (size_t)z * T_SEQ * EMB;
  float* sw = (float*)smem + w * (32 * 36);
  int orow = lane >> 1, ocol = (lane & 1) * 16;
#pragma unroll
  for (int dt = 0; dt < 2; dt++) {
    __syncthreads();
#pragma unroll
    for (int r = 0; r < 16; r++) {
      int dl = (r & 3) + 8 * (r >> 2) + 4 * hi;
      sw[ql * 36 + dl] = dt ? oT1[r] : oT0[r];
    }
    __syncthreads();
#pragma unroll
    for (int cc = 0; cc < 4; cc++) {
      f32x4 vv = *(const f32x4*)(sw + orow * 36 + ocol + cc * 4);
      *(f32x4*)(Od + (size_t)(wq0 + orow) * EMB + h * HD + dt * 32 + ocol + cc * 4) = vv;
    }
  }
}

// ---------------- combine the 2 kv-split partials ----------------
__global__ __launch_bounds__(256) void combine_kernel(const float* __restrict__ Opart,
                                                      const float* __restrict__ Mst,
                                                      const float* __restrict__ Lst,
                                                      float* __restrict__ out) {
  int i = (blockIdx.x * 256 + threadIdx.x) * 8;
  int t = i >> 10, e = i & (EMB - 1), h = e >> 6;
  float m0 = Mst[(size_t)h * T_SEQ + t], m1 = Mst[(size_t)(NH + h) * T_SEQ + t];
  float l0 = Lst[(size_t)h * T_SEQ + t], l1 = Lst[(size_t)(NH + h) * T_SEQ + t];
  float mF = fmaxf(m0, m1);
  float w0 = EXP2F(m0 - mF), w1 = EXP2F(m1 - mF);
  float inv = 1.0f / (l0 * w0 + l1 * w1);
  w0 *= inv; w1 *= inv;
  const float* O1 = Opart + (size_t)T_SEQ * EMB;
  f32x4 a0 = *(const f32x4*)(Opart + i), a1 = *(const f32x4*)(Opart + i + 4);
  f32x4 b0 = *(const f32x4*)(O1 + i),    b1 = *(const f32x4*)(O1 + i + 4);
  f32x4 r0, r1;
#pragma unroll
  for (int j = 0; j < 4; j++) { r0[j] = a0[j] * w0 + b0[j] * w1; r1[j] = a1[j] * w0 + b1[j] * w1; }
  *(f32x4*)(out + i) = r0;
  *(f32x4*)(out + i + 4) = r1;
}

extern "C" void kernel_launch(void* const* d_in, const int* in_sizes, int n_in,
                              void* d_out, int out_size, void* d_ws, size_t ws_size,
                              hipStream_t stream) {
  const float* x  = (const float*)d_in[0];
  const float* Wq = (const float*)d_in[1];
  const float* Wk = (const float*)d_in[2];
  const float* Wv = (const float*)d_in[3];
  float* out = (float*)d_out;

  unsigned short* Qb = (unsigned short*)d_ws;
  unsigned short* Kb = Qb + (size_t)T_SEQ * EMB;
  unsigned short* Vb = Kb + (size_t)T_SEQ * EMB;   // plain V from gemm (z=2)
  unsigned short* VT = Vb + (size_t)T_SEQ * EMB;   // VT[1024][4096]
  unsigned short* Xb = VT + (size_t)T_SEQ * EMB;
  unsigned short* WT = Xb + (size_t)T_SEQ * EMB;   // 3 x EMB*EMB bf16
  float* Opart = (float*)(WT + (size_t)3 * EMB * EMB);  // 2 x T x EMB f32
  float* Mst = Opart + (size_t)2 * T_SEQ * EMB;         // 2 x NH x T
  float* Lst = Mst + (size_t)2 * NH * T_SEQ;

  cast_x_kernel<<<(T_SEQ * EMB) / (256 * 8), 256, 0, stream>>>(x, Xb);
  dim3 tg(EMB / 32, EMB / 32, 3);
  transpose_cast_kernel<<<tg, 256, 0, stream>>>(Wq, Wk, Wv, WT);
  dim3 gg(T_SEQ / 128, EMB / 128, 3);
  gemm_qkv<<<gg, 256, 0, stream>>>(Xb, WT, Qb);
  dim3 tv(T_SEQ / 32, HD / 32, NH);
  transpose_v_kernel<<<tv, 256, 0, stream>>>(Vb, VT);
  dim3 ag(T_SEQ / QBLK, NH, 2);
  attn_kernel<<<ag, 256, 0, stream>>>(Qb, Kb, VT, Opart, Mst, Lst);
  combine_kernel<<<(T_SEQ * EMB) / (256 * 8), 256, 0, stream>>>(Opart, Mst, Lst, out);
}

// Round 8
// 213.242 us; speedup vs baseline: 1.3373x; 1.1510x over previous
//
#include <hip/hip_runtime.h>
#include <hip/hip_bf16.h>

#define T_SEQ 4096
#define EMB 1024
#define NH 16
#define HD 64
#define QBLK 128
#define KVB 64
#define ZS 4
#define DEFER_THR 10.0f

typedef float f32x4 __attribute__((ext_vector_type(4)));
typedef float f32x16 __attribute__((ext_vector_type(16)));
typedef short short8 __attribute__((ext_vector_type(8)));
typedef short short4v __attribute__((ext_vector_type(4)));

__device__ inline unsigned short f2bf(float f) {
  union { float f; unsigned u; } a; a.f = f;
  unsigned r = a.u + 0x7fffu + ((a.u >> 16) & 1u);
  return (unsigned short)(r >> 16);
}
#if __has_builtin(__builtin_amdgcn_exp2f)
#define EXP2F(x) __builtin_amdgcn_exp2f(x)
#else
#define EXP2F(x) exp2f(x)
#endif
#define GLL16(g, l) __builtin_amdgcn_global_load_lds( \
    (const __attribute__((address_space(1))) void*)(g), \
    (__attribute__((address_space(3))) void*)(l), 16, 0, 0)

// ---------------- cast x (f32 -> bf16) ----------------
__global__ __launch_bounds__(256) void cast_x_kernel(const float* __restrict__ in,
                                                     unsigned short* __restrict__ out) {
  int i = (blockIdx.x * 256 + threadIdx.x) * 8;
  float4 a = *(const float4*)(in + i);
  float4 b = *(const float4*)(in + i + 4);
  uint4 o;
  o.x = f2bf(a.x) | ((unsigned)f2bf(a.y) << 16);
  o.y = f2bf(a.z) | ((unsigned)f2bf(a.w) << 16);
  o.z = f2bf(b.x) | ((unsigned)f2bf(b.y) << 16);
  o.w = f2bf(b.z) | ((unsigned)f2bf(b.w) << 16);
  *(uint4*)(out + i) = o;
}

// ---------------- transpose + cast W (f32 [K][N] -> bf16 [N][K]) ----------------
__global__ __launch_bounds__(256) void transpose_cast_kernel(const float* __restrict__ Wq,
                                                             const float* __restrict__ Wk,
                                                             const float* __restrict__ Wv,
                                                             unsigned short* __restrict__ WTall) {
  int z = blockIdx.z;
  const float* W = (z == 0) ? Wq : ((z == 1) ? Wk : Wv);
  unsigned short* WT = WTall + (size_t)z * EMB * EMB;
  __shared__ unsigned short tile[32][33];
  int tx = threadIdx.x & 31, ty = threadIdx.x >> 5;
  int bn = blockIdx.x * 32, bk = blockIdx.y * 32;
#pragma unroll
  for (int p = 0; p < 4; p++)
    tile[ty + p * 8][tx] = f2bf(W[(size_t)(bk + ty + p * 8) * EMB + bn + tx]);
  __syncthreads();
#pragma unroll
  for (int p = 0; p < 4; p++)
    WT[(size_t)(bn + ty + p * 8) * EMB + bk + tx] = tile[tx][ty + p * 8];
}

// ---------------- bf16 V [t][e] -> VT [e][t] ----------------
__global__ __launch_bounds__(256) void transpose_v_kernel(const unsigned short* __restrict__ V,
                                                          unsigned short* __restrict__ VT) {
  int h = blockIdx.z;
  int t0 = blockIdx.x * 32, d0 = blockIdx.y * 32;
  __shared__ unsigned short tl[32][33];
  int tx = threadIdx.x & 31, ty = threadIdx.x >> 5;
#pragma unroll
  for (int p = 0; p < 4; p++)
    tl[ty + p * 8][tx] = V[(size_t)(t0 + ty + p * 8) * EMB + h * HD + d0 + tx];
  __syncthreads();
#pragma unroll
  for (int p = 0; p < 4; p++)
    VT[(size_t)(h * HD + d0 + ty + p * 8) * T_SEQ + t0 + tx] = tl[tx][ty + p * 8];
}

// ---------------- QKV GEMM (m97-style global_load_lds staging) ----------------
__global__ __launch_bounds__(256) void gemm_qkv(const unsigned short* __restrict__ Xb,
                                                const unsigned short* __restrict__ WTall,
                                                unsigned short* __restrict__ QKV) {
  int z = blockIdx.z;
  const unsigned short* Bt = WTall + (size_t)z * EMB * EMB;
  unsigned short* Out = QKV + (size_t)z * T_SEQ * EMB;

  __shared__ __align__(16) unsigned short sA[128 * 32];
  __shared__ __align__(16) unsigned short sB[128 * 32];

  int m0 = blockIdx.x * 128, n0 = blockIdx.y * 128;
  int tid = threadIdx.x;
  int lane = tid & 63, wid = tid >> 6;
  int wr = wid >> 1, wc = wid & 1;
  int fr = lane & 15, fq = lane >> 4;

  int r0 = tid >> 2, o0 = (tid & 3) * 8;
  int r1 = (tid + 256) >> 2;

  f32x4 acc[4][4] = {};

  for (int k0 = 0; k0 < EMB; k0 += 32) {
    __syncthreads();
    GLL16(Xb + (size_t)(m0 + r0) * EMB + k0 + o0, sA + (size_t)tid * 8);
    GLL16(Xb + (size_t)(m0 + r1) * EMB + k0 + o0, sA + (size_t)(tid + 256) * 8);
    GLL16(Bt + (size_t)(n0 + r0) * EMB + k0 + o0, sB + (size_t)tid * 8);
    GLL16(Bt + (size_t)(n0 + r1) * EMB + k0 + o0, sB + (size_t)(tid + 256) * 8);
    asm volatile("s_waitcnt vmcnt(0)" ::: "memory");
    __syncthreads();

    short8 aF[4], bF[4];
#pragma unroll
    for (int i = 0; i < 4; i++) {
      aF[i] = *(const short8*)(sA + (wr * 64 + i * 16 + fr) * 32 + fq * 8);
      bF[i] = *(const short8*)(sB + (wc * 64 + i * 16 + fr) * 32 + fq * 8);
    }
#pragma unroll
    for (int i = 0; i < 4; i++)
#pragma unroll
      for (int j = 0; j < 4; j++)
        acc[i][j] = __builtin_amdgcn_mfma_f32_16x16x32_bf16(aF[i], bF[j], acc[i][j], 0, 0, 0);
  }

  float scale = (z == 0) ? 0.1803368801111204f : 1.0f;  // 0.125 * log2(e) for Q
#pragma unroll
  for (int i = 0; i < 4; i++)
#pragma unroll
    for (int j = 0; j < 4; j++)
#pragma unroll
      for (int r = 0; r < 4; r++) {
        int row = m0 + wr * 64 + i * 16 + fq * 4 + r;
        int col = n0 + wc * 64 + j * 16 + fr;
        Out[(size_t)row * EMB + col] = f2bf(acc[i][j][r] * scale);
      }
}

// ---------------- causal flash attention, swapped-QK 32x32x16 ----------------
// grid (16 pairs, 16 heads, ZS=4). Block (p,h,z) processes columns {p, 31-p}
// sequentially; per column, kv tiles t = z, z+ZS, ... < 2c+2. Work = 66/ZS tiles
// per block, CONSTANT -> flat occupancy. 4 waves x 32 q; LDS-staged K/V^T.
__global__ __launch_bounds__(256) void attn_kernel(const unsigned short* __restrict__ Qb,
                                                   const unsigned short* __restrict__ Kb,
                                                   const unsigned short* __restrict__ VTg,
                                                   float* __restrict__ Opart,
                                                   float* __restrict__ Mst,
                                                   float* __restrict__ Lst) {
  int p = blockIdx.x;
  int h = blockIdx.y;
  int z = blockIdx.z;
  int tid = threadIdx.x;
  int lane = tid & 63, w = tid >> 6;
  int ql = lane & 31, hi = lane >> 5;

  __shared__ __align__(16) unsigned short smem[14336];  // 28672 B
  unsigned short* sK = smem;                      // [64][72]
  unsigned short* sVT = smem + 64 * 72;           // [64][72] (V^T: [d][kv])
  unsigned short* sP = smem + 2 * 64 * 72 + w * (32 * 40);  // per-wave [32 q][32 kv] pad 40

  int sr = tid >> 3;            // staging: 8 lanes x 16B = one 128B row
  int scs = (tid & 7) * 8;

#pragma unroll 1
  for (int side = 0; side < 2; side++) {
    int c = side ? (31 - p) : p;
    int q0 = c * QBLK;
    int wq0 = q0 + w * 32;
    int qg = wq0 + ql;
    int wqmax = wq0 + 31;
    int ntot = 2 * c + 2;

    short8 qf[4];  // B-frags of Q: Q[q=ql][d = ks*16 + hi*8 + j]
#pragma unroll
    for (int ks = 0; ks < 4; ks++)
      qf[ks] = *(const short8*)(Qb + (size_t)qg * EMB + h * HD + ks * 16 + hi * 8);

    f32x16 oT0 = {}, oT1 = {};  // O^T accumulators, d-tiles 0/1, col = q = ql
    float m = -1e30f, lsum = 0.f;

    // prologue: issue loads for first owned tile (t = z; kv < 256, always in-bounds)
    int kvp = z * KVB;
    short8 ka = *(const short8*)(Kb + (size_t)(kvp + sr) * EMB + h * HD + scs);
    short8 kb = *(const short8*)(Kb + (size_t)(kvp + sr + 32) * EMB + h * HD + scs);
    short8 va = *(const short8*)(VTg + (size_t)(h * HD + sr) * T_SEQ + kvp + scs);
    short8 vb = *(const short8*)(VTg + (size_t)(h * HD + sr + 32) * T_SEQ + kvp + scs);

    for (int t = z; t < ntot; t += ZS) {
      int kv0c = t * KVB;
      __syncthreads();  // all waves done reading previous tile
      *(short8*)(sK + sr * 72 + scs) = ka;
      *(short8*)(sK + (sr + 32) * 72 + scs) = kb;
      *(short8*)(sVT + sr * 72 + scs) = va;
      *(short8*)(sVT + (sr + 32) * 72 + scs) = vb;
      __syncthreads();  // publish

      if (t + ZS < ntot) {  // prefetch next owned tile
        int kv1 = kv0c + ZS * KVB;
        ka = *(const short8*)(Kb + (size_t)(kv1 + sr) * EMB + h * HD + scs);
        kb = *(const short8*)(Kb + (size_t)(kv1 + sr + 32) * EMB + h * HD + scs);
        va = *(const short8*)(VTg + (size_t)(h * HD + sr) * T_SEQ + kv1 + scs);
        vb = *(const short8*)(VTg + (size_t)(h * HD + sr + 32) * T_SEQ + kv1 + scs);
      }

#pragma unroll
      for (int s = 0; s < 2; s++) {
        int kvs = kv0c + s * 32;
        if (kvs <= wqmax) {  // wave-uniform causal skip
          f32x16 st = {};
          __builtin_amdgcn_s_setprio(1);
#pragma unroll
          for (int ks = 0; ks < 4; ks++) {
            short8 kf = *(const short8*)(sK + (s * 32 + ql) * 72 + ks * 16 + hi * 8);
            st = __builtin_amdgcn_mfma_f32_32x32x16_bf16(kf, qf[ks], st, 0, 0, 0);
          }
          __builtin_amdgcn_s_setprio(0);
          if (kvs + 31 > wq0) {  // diagonal tile: mask kv > q
#pragma unroll
            for (int r = 0; r < 16; r++) {
              int kvg = kvs + (r & 3) + 8 * (r >> 2) + 4 * hi;
              if (kvg > qg) st[r] = -1e30f;
            }
          }
          float a0 = fmaxf(fmaxf(st[0], st[1]), st[2]);
          float a1 = fmaxf(fmaxf(st[3], st[4]), st[5]);
          float a2 = fmaxf(fmaxf(st[6], st[7]), st[8]);
          float a3 = fmaxf(fmaxf(st[9], st[10]), st[11]);
          float a4 = fmaxf(fmaxf(st[12], st[13]), st[14]);
          float mt = fmaxf(fmaxf(fmaxf(a0, a1), a2), fmaxf(fmaxf(a3, a4), st[15]));
          mt = fmaxf(mt, __shfl_xor(mt, 32));
          if (!__all(mt - m <= DEFER_THR)) {  // defer-max (T13)
            float mnew = fmaxf(m, mt);
            float al = EXP2F(m - mnew);
            lsum *= al;
#pragma unroll
            for (int r = 0; r < 16; r++) { oT0[r] *= al; oT1[r] *= al; }
            m = mnew;
          }
#pragma unroll
          for (int r = 0; r < 16; r++) st[r] = EXP2F(st[r] - m);
          float s0 = (st[0] + st[1]) + (st[2] + st[3]);
          float s1 = (st[4] + st[5]) + (st[6] + st[7]);
          float s2 = (st[8] + st[9]) + (st[10] + st[11]);
          float s3 = (st[12] + st[13]) + (st[14] + st[15]);
          float ls = (s0 + s1) + (s2 + s3);
          ls += __shfl_xor(ls, 32);
          lsum += ls;

          // P^T -> bf16 via per-wave LDS round-trip: sP[q=ql][kv_local]
#pragma unroll
          for (int g = 0; g < 4; g++) {
            __hip_bfloat162 plo = __float22bfloat162_rn(float2{st[g * 4 + 0], st[g * 4 + 1]});
            __hip_bfloat162 phi = __float22bfloat162_rn(float2{st[g * 4 + 2], st[g * 4 + 3]});
            union { __hip_bfloat162 hh[2]; short4v s4; } u4;
            u4.hh[0] = plo; u4.hh[1] = phi;
            *(short4v*)(sP + ql * 40 + g * 8 + hi * 4) = u4.s4;
          }
          asm volatile("s_waitcnt lgkmcnt(0)" ::: "memory");  // wave-local round-trip
          __builtin_amdgcn_sched_barrier(0);

          __builtin_amdgcn_s_setprio(1);
#pragma unroll
          for (int ksp = 0; ksp < 2; ksp++) {
            short8 pa = *(const short8*)(sP + ql * 40 + ksp * 16 + hi * 8);
            int cb = s * 32 + ksp * 16 + hi * 8;
            short8 v0 = *(const short8*)(sVT + (0 * 32 + ql) * 72 + cb);
            short8 v1 = *(const short8*)(sVT + (1 * 32 + ql) * 72 + cb);
            oT0 = __builtin_amdgcn_mfma_f32_32x32x16_bf16(v0, pa, oT0, 0, 0, 0);
            oT1 = __builtin_amdgcn_mfma_f32_32x32x16_bf16(v1, pa, oT1, 0, 0, 0);
          }
          __builtin_amdgcn_s_setprio(0);
        }
      }
    }

    // stats for this column
    if (hi == 0) {
      Mst[((size_t)z * NH + h) * T_SEQ + qg] = m;
      Lst[((size_t)z * NH + h) * T_SEQ + qg] = lsum;
    }

    // epilogue: transpose raw O^T -> O through LDS, coalesced f32x4 stores to Opart
    float* Od = Opart + (size_t)z * T_SEQ * EMB;
    float* sw = (float*)smem + w * (32 * 36);
    int orow = lane >> 1, ocol = (lane & 1) * 16;
#pragma unroll
    for (int dt = 0; dt < 2; dt++) {
      __syncthreads();
#pragma unroll
      for (int r = 0; r < 16; r++) {
        int dl = (r & 3) + 8 * (r >> 2) + 4 * hi;
        sw[ql * 36 + dl] = dt ? oT1[r] : oT0[r];
      }
      __syncthreads();
#pragma unroll
      for (int cc = 0; cc < 4; cc++) {
        f32x4 vv = *(const f32x4*)(sw + orow * 36 + ocol + cc * 4);
        *(f32x4*)(Od + (size_t)(wq0 + orow) * EMB + h * HD + dt * 32 + ocol + cc * 4) = vv;
      }
    }
  }
}

// ---------------- combine the ZS kv-split partials ----------------
__global__ __launch_bounds__(256) void combine_kernel(const float* __restrict__ Opart,
                                                      const float* __restrict__ Mst,
                                                      const float* __restrict__ Lst,
                                                      float* __restrict__ out) {
  int i = (blockIdx.x * 256 + threadIdx.x) * 8;
  int t = i >> 10, e = i & (EMB - 1), h = e >> 6;
  float mz[ZS], lz[ZS];
#pragma unroll
  for (int z = 0; z < ZS; z++) {
    mz[z] = Mst[((size_t)z * NH + h) * T_SEQ + t];
    lz[z] = Lst[((size_t)z * NH + h) * T_SEQ + t];
  }
  float mF = fmaxf(fmaxf(mz[0], mz[1]), fmaxf(mz[2], mz[3]));
  float wz[ZS], denom = 0.f;
#pragma unroll
  for (int z = 0; z < ZS; z++) { wz[z] = EXP2F(mz[z] - mF); denom += lz[z] * wz[z]; }
  float inv = 1.0f / denom;
  f32x4 r0 = {}, r1 = {};
#pragma unroll
  for (int z = 0; z < ZS; z++) {
    const float* Oz = Opart + (size_t)z * T_SEQ * EMB;
    f32x4 a0 = *(const f32x4*)(Oz + i), a1 = *(const f32x4*)(Oz + i + 4);
    float wgt = wz[z] * inv;
#pragma unroll
    for (int j = 0; j < 4; j++) { r0[j] += a0[j] * wgt; r1[j] += a1[j] * wgt; }
  }
  *(f32x4*)(out + i) = r0;
  *(f32x4*)(out + i + 4) = r1;
}

extern "C" void kernel_launch(void* const* d_in, const int* in_sizes, int n_in,
                              void* d_out, int out_size, void* d_ws, size_t ws_size,
                              hipStream_t stream) {
  const float* x  = (const float*)d_in[0];
  const float* Wq = (const float*)d_in[1];
  const float* Wk = (const float*)d_in[2];
  const float* Wv = (const float*)d_in[3];
  float* out = (float*)d_out;

  unsigned short* Qb = (unsigned short*)d_ws;
  unsigned short* Kb = Qb + (size_t)T_SEQ * EMB;
  unsigned short* Vb = Kb + (size_t)T_SEQ * EMB;   // plain V from gemm (z=2)
  unsigned short* VT = Vb + (size_t)T_SEQ * EMB;   // VT[1024][4096]
  unsigned short* Xb = VT + (size_t)T_SEQ * EMB;
  unsigned short* WT = Xb + (size_t)T_SEQ * EMB;   // 3 x EMB*EMB bf16
  float* Opart = (float*)(WT + (size_t)3 * EMB * EMB);  // ZS x T x EMB f32
  float* Mst = Opart + (size_t)ZS * T_SEQ * EMB;        // ZS x NH x T
  float* Lst = Mst + (size_t)ZS * NH * T_SEQ;

  cast_x_kernel<<<(T_SEQ * EMB) / (256 * 8), 256, 0, stream>>>(x, Xb);
  dim3 tg(EMB / 32, EMB / 32, 3);
  transpose_cast_kernel<<<tg, 256, 0, stream>>>(Wq, Wk, Wv, WT);
  dim3 gg(T_SEQ / 128, EMB / 128, 3);
  gemm_qkv<<<gg, 256, 0, stream>>>(Xb, WT, Qb);
  dim3 tv(T_SEQ / 32, HD / 32, NH);
  transpose_v_kernel<<<tv, 256, 0, stream>>>(Vb, VT);
  dim3 ag(T_SEQ / QBLK / 2, NH, ZS);
  attn_kernel<<<ag, 256, 0, stream>>>(Qb, Kb, VT, Opart, Mst, Lst);
  combine_kernel<<<(T_SEQ * EMB) / (256 * 8), 256, 0, stream>>>(Opart, Mst, Lst, out);
}